// Round 5
// baseline (96.208 us; speedup 1.0000x reference)
//
#include <hip/hip_runtime.h>
#include <hip/hip_bf16.h>

// Round 5: two-kernel split to kill the build-phase dependent-load chain.
//  K1 build_kernel: grid-stride, no barriers -> mixed_g[row][32] bf16 (A-frag-
//     ready) + tail_g[row][2] f32 in d_ws. Latency hidden by pure occupancy.
//  K2 mlp_kernel: A-frags loaded directly from global (coalesced 1KB/wave),
//     W1f B-frags (hardware-verified layout) in LDS, no per-tile barriers.
//     Verified varA epilogue + f32 rank-2 tail + shfl reduce.

#define B_ROWS 262144
#define DFEAT  181
#define BASICF 13
#define NG     21
#define MIXF   34
#define HID    512

typedef __attribute__((ext_vector_type(8))) short short8;
typedef __attribute__((ext_vector_type(4))) float float4_t;

__device__ __forceinline__ short f2bf(float f) {
    union { float f; unsigned u; } v; v.f = f;
    unsigned r = (v.u + 0x7FFFu + ((v.u >> 16) & 1u)) >> 16;  // RNE
    return (short)r;
}
__device__ __forceinline__ float sigm(float x) { return 1.0f / (1.0f + __expf(-x)); }

// ---------------- K1: build mixed features (streaming, no barriers) ----------------
#define BUILD_BLOCKS 2048
__global__ __launch_bounds__(256) void build_kernel(
    const float* __restrict__ data, const float* __restrict__ gW,
    const float* __restrict__ gb, short* __restrict__ mixed_g,
    float* __restrict__ tail_g)
{
    __shared__ float gws[NG * 8];
    __shared__ float gbs[NG];
    if (threadIdx.x < NG * 8) gws[threadIdx.x] = gW[threadIdx.x];
    if (threadIdx.x < NG)     gbs[threadIdx.x] = gb[threadIdx.x];
    __syncthreads();

    const int total  = B_ROWS * MIXF;            // 8,912,896
    const int stride = BUILD_BLOCKS * 256;
    for (int u = blockIdx.x * 256 + threadIdx.x; u < total; u += stride) {
        int row = u / MIXF;
        int c   = u - row * MIXF;
        const float* dr = data + (size_t)row * DFEAT;
        if (c < BASICF) {
            mixed_g[row * 32 + c] = f2bf(dr[c]);
        } else {
            int g = c - BASICF;
            const float* x = dr + BASICF + g * 8;
            float s = gbs[g];
            #pragma unroll
            for (int k = 0; k < 8; ++k) s = fmaf(x[k], gws[g * 8 + k], s);
            float v = sigm(s);
            if (c < 32) mixed_g[row * 32 + c] = f2bf(v);
            else        tail_g[row * 2 + (c - 32)] = v;
        }
    }
}

// ---------------- K2: MFMA Linear(34->512)+ReLU -> Linear(512->1)+sigmoid ----------------
#define MLP_BLOCKS 1024
__global__ __launch_bounds__(256) void mlp_kernel(
    const short* __restrict__ mixed_g, const float* __restrict__ tail_g,
    const float* __restrict__ W1, const float* __restrict__ b1,
    const float* __restrict__ W2, const float* __restrict__ b2,
    float* __restrict__ out)
{
    // LDS: 32KB + 8KB = 40KB -> 4 blocks/CU
    __shared__ __align__(16) short   W1f[32 * 64 * 8];  // B-frags k=0..31 (verified layout)
    __shared__ __align__(16) float4_t wbt[HID];         // {b1, W2, W1[32][c], W1[33][c]}

    const int tid = threadIdx.x;
    for (int idx = tid; idx < 32 * HID; idx += 256) {
        int k = idx >> 9, c = idx & 511;
        int t = c >> 4, ci = c & 15;
        int l = ((k >> 3) << 4) + ci;
        int j = k & 7;
        W1f[(t * 64 + l) * 8 + j] = f2bf(W1[k * HID + c]);
    }
    for (int c = tid; c < HID; c += 256)
        wbt[c] = (float4_t){ b1[c], W2[c], W1[32 * HID + c], W1[33 * HID + c] };
    __syncthreads();

    const int wave = tid >> 6;
    const int lane = tid & 63;
    const int lg   = lane >> 4;   // 0..3
    const int li   = lane & 15;
    const float b2v = b2[0];

    #pragma unroll 1
    for (int it = 0; it < 4; ++it) {
        const int task = (blockIdx.x * 4 + wave) * 4 + it;  // 0..16383
        const int row0 = task * 16;

        // A-frag direct from global (verified layout): lane l -> A[row=li][k=lg*8+j]
        // wave reads contiguous 1KB: ((row0+li)*32 + lg*8) shorts
        short8 a0 = *(const short8*)&mixed_g[(row0 + li) * 32 + lg * 8];
        float2 mt[4];
        #pragma unroll
        for (int j = 0; j < 4; ++j)
            mt[j] = *(const float2*)&tail_g[(row0 + lg * 4 + j) * 2];

        float4_t acc = {0.f, 0.f, 0.f, 0.f};
        for (int t = 0; t < 32; ++t) {
            short8 bf = *(const short8*)&W1f[(t * 64 + lane) * 8];
            float4_t c4 = {0.f, 0.f, 0.f, 0.f};
            c4 = __builtin_amdgcn_mfma_f32_16x16x32_bf16(a0, bf, c4, 0, 0, 0);
            // C-frag (verified): lane l holds C[row=lg*4+j][col=t*16+li]
            int c = t * 16 + li;
            float4_t wv = wbt[c];  // {b1, W2, w32, w33}
            #pragma unroll
            for (int j = 0; j < 4; ++j) {
                float h = c4[j] + wv.x;
                h = fmaf(mt[j].x, wv.z, h);
                h = fmaf(mt[j].y, wv.w, h);
                h = fmaxf(h, 0.f);
                acc[j] = fmaf(h, wv.y, acc[j]);
            }
        }
        // reduce layer-2 partials across the 16 col-lanes (verified)
        #pragma unroll
        for (int m = 1; m < 16; m <<= 1) {
            #pragma unroll
            for (int j = 0; j < 4; ++j) acc[j] += __shfl_xor(acc[j], m, 64);
        }
        if (li == 0) {
            #pragma unroll
            for (int j = 0; j < 4; ++j)
                out[row0 + lg * 4 + j] = sigm(acc[j] + b2v);
        }
    }
}

extern "C" void kernel_launch(void* const* d_in, const int* in_sizes, int n_in,
                              void* d_out, int out_size, void* d_ws, size_t ws_size,
                              hipStream_t stream) {
    (void)in_sizes; (void)n_in; (void)out_size; (void)ws_size;
    const float* data = (const float*)d_in[0];
    const float* gW   = (const float*)d_in[1];
    const float* gb   = (const float*)d_in[2];
    const float* W1   = (const float*)d_in[3];
    const float* b1   = (const float*)d_in[4];
    const float* W2   = (const float*)d_in[5];
    const float* b2   = (const float*)d_in[6];
    float* out = (float*)d_out;

    short* mixed_g = (short*)d_ws;                       // 16 MB: [B_ROWS][32] bf16
    float* tail_g  = (float*)((char*)d_ws + (size_t)B_ROWS * 32 * 2);  // 2 MB: [B_ROWS][2] f32

    build_kernel<<<dim3(BUILD_BLOCKS), dim3(256), 0, stream>>>(data, gW, gb, mixed_g, tail_g);
    mlp_kernel<<<dim3(MLP_BLOCKS), dim3(256), 0, stream>>>(mixed_g, tail_g, W1, b1, W2, b2, out);
}

// Round 6
// 89.875 us; speedup vs baseline: 1.0705x; 1.0705x over previous
//
#include <hip/hip_runtime.h>
#include <hip/hip_bf16.h>

// Round 6: revert to round-4 fused structure (51.7us verified) + two fixes:
//  (1) second MFMA folds rank-2 tail {m32,m33} AND bias b1 into the
//      pre-activation: c4 = mfma(a0,bf, mfma(a2,bf2,0)). Epilogue per col-tile
//      drops 20 -> 8 VALU. Lanes lg>=1 read B2f unconditioned: A2 cols k>=3
//      are zero for all rows, so their products vanish.
//  (2) occupancy 16 -> 24 waves/CU: LDS ~52KB (3 blocks/CU), grid 1024 x 256
//      rows, __launch_bounds__(512,6) to cap VGPR at 85.

#define B_ROWS 262144
#define DFEAT  181
#define BASICF 13
#define NG     21
#define MIXF   34
#define HID    512
#define NT     512
#define TILE   128
#define ROWS_PER_BLOCK 256
#define NTILES (ROWS_PER_BLOCK / TILE)   // 2
#define NBLK   (B_ROWS / ROWS_PER_BLOCK) // 1024

typedef __attribute__((ext_vector_type(8))) short short8;
typedef __attribute__((ext_vector_type(4))) float float4_t;

__device__ __forceinline__ short f2bf(float f) {
    union { float f; unsigned u; } v; v.f = f;
    unsigned r = (v.u + 0x7FFFu + ((v.u >> 16) & 1u)) >> 16;  // RNE
    return (short)r;
}
__device__ __forceinline__ float sigm(float x) { return 1.0f / (1.0f + __expf(-x)); }

__global__ __launch_bounds__(NT, 6) void fused_mfma_kernel(
    const float* __restrict__ data, const float* __restrict__ gW,
    const float* __restrict__ gb, const float* __restrict__ W1,
    const float* __restrict__ b1, const float* __restrict__ W2,
    const float* __restrict__ b2, float* __restrict__ out)
{
    // LDS ~52KB -> 3 blocks/CU
    __shared__ __align__(16) short W1f[32 * 64 * 8];   // 32KB  B-frags k=0..31 (verified layout)
    __shared__ __align__(16) short B2f[32 * 16 * 8];   // 8KB   {W1[32][c],W1[33][c],b1[c],0...} frags
    __shared__ float W2s[HID];                         // 2KB
    __shared__ __align__(16) short mixed[TILE * 32];   // 8KB   A tile [128 rows][k 0..31] bf16
    __shared__ __align__(8)  short mtailb[TILE * 4];   // 1KB   {m32,m33,1.0,0} bf16 per row
    __shared__ float gws[NG * 8];
    __shared__ float gbs[NG];

    const int tid = threadIdx.x;

    // ---- one-time staging ----
    for (int idx = tid; idx < 32 * HID; idx += NT) {   // W1f, verified B-frag layout
        int k = idx >> 9, c = idx & 511;
        int t = c >> 4, ci = c & 15;
        int l = ((k >> 3) << 4) + ci;
        int j = k & 7;
        W1f[(t * 64 + l) * 8 + j] = f2bf(W1[k * HID + c]);
    }
    {
        int c = tid;  // NT == HID: one B2 fragment row per thread
        int t = c >> 4, ci = c & 15;
        short8 v = {0, 0, 0, 0, 0, 0, 0, 0};
        v[0] = f2bf(W1[32 * HID + c]);
        v[1] = f2bf(W1[33 * HID + c]);
        v[2] = f2bf(b1[c]);
        *(short8*)&B2f[(t * 16 + ci) * 8] = v;
        W2s[c] = W2[c];
    }
    if (tid < TILE) ((int*)mtailb)[tid * 2 + 1] = 0x00003F80;  // {1.0bf16, 0} once
    if (tid < NG * 8) gws[tid] = gW[tid];
    if (tid < NG)     gbs[tid] = gb[tid];
    __syncthreads();

    const int wave = tid >> 6;
    const int lane = tid & 63;
    const int lg   = lane >> 4;  // 0..3
    const int li   = lane & 15;
    const float b2v = b2[0];
    const int blk_row0 = blockIdx.x * ROWS_PER_BLOCK;

    // ---- build tile 0 ----
    {
        const int row0 = blk_row0;
        for (int it = 0; it < 9; ++it) {
            int u = tid + it * NT;
            if (u < TILE * MIXF) {
                int row = u / MIXF, c = u - row * MIXF;
                const float* dr = data + (size_t)(row0 + row) * DFEAT;
                if (c < BASICF) {
                    mixed[row * 32 + c] = f2bf(dr[c]);
                } else {
                    int g = c - BASICF;
                    const float* x = dr + BASICF + g * 8;
                    float s = gbs[g];
                    #pragma unroll
                    for (int k = 0; k < 8; ++k) s = fmaf(x[k], gws[g * 8 + k], s);
                    float v = sigm(s);
                    if (c < 32) mixed[row * 32 + c] = f2bf(v);
                    else        mtailb[row * 4 + (c - 32)] = f2bf(v);
                }
            }
        }
    }
    __syncthreads();

    for (int tile = 0; tile < NTILES; ++tile) {
        const int trow0 = blk_row0 + tile * TILE;

        // A-frags (verified layout): lane l, reg j -> A[row=l&15][k=(l>>4)*8+j]
        short8 a0 = *(const short8*)&mixed[(wave * 16 + li) * 32 + lg * 8];
        short8 a2;
        {
            union { int i[4]; short8 s; } ua;
            const int* mp = (const int*)&mtailb[(wave * 16 + li) * 4];
            ua.i[0] = (lg == 0) ? mp[0] : 0;   // {m32, m33} bf16 pair
            ua.i[1] = (lg == 0) ? mp[1] : 0;   // {1.0, 0} bf16 pair
            ua.i[2] = 0; ua.i[3] = 0;
            a2 = ua.s;
        }
        __syncthreads();  // all A-frags secured; mixed/mtailb free for overwrite

        // build tile t+1 (overlaps MFMA below)
        if (tile + 1 < NTILES) {
            const int row0 = trow0 + TILE;
            for (int it = 0; it < 9; ++it) {
                int u = tid + it * NT;
                if (u < TILE * MIXF) {
                    int row = u / MIXF, c = u - row * MIXF;
                    const float* dr = data + (size_t)(row0 + row) * DFEAT;
                    if (c < BASICF) {
                        mixed[row * 32 + c] = f2bf(dr[c]);
                    } else {
                        int g = c - BASICF;
                        const float* x = dr + BASICF + g * 8;
                        float s = gbs[g];
                        #pragma unroll
                        for (int k = 0; k < 8; ++k) s = fmaf(x[k], gws[g * 8 + k], s);
                        float v = sigm(s);
                        if (c < 32) mixed[row * 32 + c] = f2bf(v);
                        else        mtailb[row * 4 + (c - 32)] = f2bf(v);
                    }
                }
            }
        }

        // MFMA over 32 col-tiles; c4 = full pre-activation (bias+tail folded in)
        float4_t acc = {0.f, 0.f, 0.f, 0.f};
        for (int t = 0; t < 32; ++t) {
            short8 bf2 = *(const short8*)&B2f[(t * 16 + li) * 8];  // all lanes: k>=3 of A2 is 0
            short8 bf  = *(const short8*)&W1f[(t * 64 + lane) * 8];
            float4_t c4 = {0.f, 0.f, 0.f, 0.f};
            c4 = __builtin_amdgcn_mfma_f32_16x16x32_bf16(a2, bf2, c4, 0, 0, 0);
            c4 = __builtin_amdgcn_mfma_f32_16x16x32_bf16(a0, bf,  c4, 0, 0, 0);
            // C-frag (verified): lane l holds C[row=(l>>4)*4+j][col=t*16+(l&15)]
            float w2 = W2s[t * 16 + li];
            #pragma unroll
            for (int j = 0; j < 4; ++j) {
                acc[j] = fmaf(fmaxf(c4[j], 0.f), w2, acc[j]);
            }
        }
        // reduce layer-2 partials across the 16 col-lanes (verified)
        #pragma unroll
        for (int m = 1; m < 16; m <<= 1) {
            #pragma unroll
            for (int j = 0; j < 4; ++j) acc[j] += __shfl_xor(acc[j], m, 64);
        }
        if (li == 0) {
            #pragma unroll
            for (int j = 0; j < 4; ++j)
                out[trow0 + wave * 16 + lg * 4 + j] = sigm(acc[j] + b2v);
        }
        __syncthreads();  // next iteration's A-frag reads need build complete
    }
}

extern "C" void kernel_launch(void* const* d_in, const int* in_sizes, int n_in,
                              void* d_out, int out_size, void* d_ws, size_t ws_size,
                              hipStream_t stream) {
    (void)in_sizes; (void)n_in; (void)out_size; (void)d_ws; (void)ws_size;
    const float* data = (const float*)d_in[0];
    const float* gW   = (const float*)d_in[1];
    const float* gb   = (const float*)d_in[2];
    const float* W1   = (const float*)d_in[3];
    const float* b1   = (const float*)d_in[4];
    const float* W2   = (const float*)d_in[5];
    const float* b2   = (const float*)d_in[6];
    float* out = (float*)d_out;
    fused_mfma_kernel<<<dim3(NBLK), dim3(NT), 0, stream>>>(data, gW, gb, W1, b1, W2, b2, out);
}

// Round 7
// 78.227 us; speedup vs baseline: 1.2299x; 1.1489x over previous
//
#include <hip/hip_runtime.h>
#include <hip/hip_bf16.h>

// Round 7: W1-stationary restructure (R6's spill disaster reverted: no
// min-waves launch_bounds clause).
//  - Each wave owns 64 output cols: W1 held in REGISTERS as 4 A-frags
//    (verified varA A-layout), loaded from global once per block.
//  - A2-frag folds {W1[32][c], W1[33][c], b1[c]} -> full pre-activation from
//    two chained MFMAs per slice; epilogue = relu+fma only.
//  - Per 16-row task: ONE ds_read_b128 (activation B-frag) + 4B tail read.
//    Hot-loop LDS traffic ~8x lower than R4; W1f/wbt LDS gone (26KB total).
//  - mixed double-buffered: build(t+1) overlaps task phase.
//  - Layer-2 cross-wave reduce via partials[8][128] + 128-thread finish.

#define B_ROWS 262144
#define DFEAT  181
#define BASICF 13
#define NG     21
#define MIXF   34
#define HID    512
#define NT     512
#define TILE   128
#define MSTRIDE 40                        // shorts per row (80B) - depads banks
#define ROWS_PER_BLOCK 512
#define NTILES (ROWS_PER_BLOCK / TILE)    // 4
#define NBLK   (B_ROWS / ROWS_PER_BLOCK)  // 512

typedef __attribute__((ext_vector_type(8))) short short8;
typedef __attribute__((ext_vector_type(4))) float float4_t;

__device__ __forceinline__ short f2bf(float f) {
    union { float f; unsigned u; } v; v.f = f;
    unsigned r = (v.u + 0x7FFFu + ((v.u >> 16) & 1u)) >> 16;  // RNE
    return (short)r;
}
__device__ __forceinline__ float sigm(float x) { return 1.0f / (1.0f + __expf(-x)); }

__global__ __launch_bounds__(NT) void fused_mfma_kernel(
    const float* __restrict__ data, const float* __restrict__ gW,
    const float* __restrict__ gb, const float* __restrict__ W1,
    const float* __restrict__ b1, const float* __restrict__ W2,
    const float* __restrict__ b2, float* __restrict__ out)
{
    // LDS ~26.3KB
    __shared__ __align__(16) short mixed[2][TILE * MSTRIDE];  // 20KB  A tiles (dbuf)
    __shared__ short mtailb[2][TILE * 2];                     // 1KB   {m32,m33} bf16/row
    __shared__ float partials[8][TILE];                       // 4KB   layer-2 partials
    __shared__ float gws[NG * 8];
    __shared__ float gbs[NG];

    const int tid  = threadIdx.x;
    const int wave = tid >> 6;
    const int lane = tid & 63;
    const int lg   = lane >> 4;   // 0..3
    const int li   = lane & 15;

    if (tid < NG * 8) gws[tid] = gW[tid];
    if (tid < NG)     gbs[tid] = gb[tid];

    // ---- W1/b1/W2 -> registers (once per block) ----
    // A-frag (verified): lane l, reg j -> A[row=l&15][k=(l>>4)*8+j], A[c][k]=W1[k][c]
    const int c0 = wave * 64;
    short8 aW[4];
    #pragma unroll
    for (int s = 0; s < 4; ++s) {
        int c = c0 + s * 16 + li;
        #pragma unroll
        for (int j = 0; j < 8; ++j)
            aW[s][j] = f2bf(W1[(lg * 8 + j) * HID + c]);
    }
    short8 a2[4];  // k=0: W1[32][c], k=1: W1[33][c], k=2: b1[c] (lg==0 only)
    #pragma unroll
    for (int s = 0; s < 4; ++s) {
        int c = c0 + s * 16 + li;
        short8 v = {0, 0, 0, 0, 0, 0, 0, 0};
        if (lg == 0) {
            v[0] = f2bf(W1[32 * HID + c]);
            v[1] = f2bf(W1[33 * HID + c]);
            v[2] = f2bf(b1[c]);
        }
        a2[s] = v;
    }
    float w2r[4][4];  // W2[c] for this lane's D rows: c = c0+s*16+lg*4+j
    #pragma unroll
    for (int s = 0; s < 4; ++s)
        #pragma unroll
        for (int j = 0; j < 4; ++j)
            w2r[s][j] = W2[c0 + s * 16 + lg * 4 + j];

    const float b2v = b2[0];
    const int blk_row0 = blockIdx.x * ROWS_PER_BLOCK;
    __syncthreads();  // gws/gbs visible

    // ---- build tile 0 ----
    {
        const int row0 = blk_row0;
        for (int it = 0; it < 9; ++it) {
            int u = tid + it * NT;
            if (u < TILE * MIXF) {
                int row = u / MIXF, c = u - row * MIXF;
                const float* dr = data + (size_t)(row0 + row) * DFEAT;
                if (c < BASICF) {
                    mixed[0][row * MSTRIDE + c] = f2bf(dr[c]);
                } else {
                    int g = c - BASICF;
                    const float* x = dr + BASICF + g * 8;
                    float s = gbs[g];
                    #pragma unroll
                    for (int k = 0; k < 8; ++k) s = fmaf(x[k], gws[g * 8 + k], s);
                    float v = sigm(s);
                    if (c < 32) mixed[0][row * MSTRIDE + c] = f2bf(v);
                    else        mtailb[0][row * 2 + (c - 32)] = f2bf(v);
                }
            }
        }
    }
    __syncthreads();

    int cur = 0;
    for (int tile = 0; tile < NTILES; ++tile) {
        const int trow0 = blk_row0 + tile * TILE;

        // build tile t+1 into the other buffer (overlaps task phase)
        if (tile + 1 < NTILES) {
            const int row0 = trow0 + TILE;
            const int nb = cur ^ 1;
            for (int it = 0; it < 9; ++it) {
                int u = tid + it * NT;
                if (u < TILE * MIXF) {
                    int row = u / MIXF, c = u - row * MIXF;
                    const float* dr = data + (size_t)(row0 + row) * DFEAT;
                    if (c < BASICF) {
                        mixed[nb][row * MSTRIDE + c] = f2bf(dr[c]);
                    } else {
                        int g = c - BASICF;
                        const float* x = dr + BASICF + g * 8;
                        float s = gbs[g];
                        #pragma unroll
                        for (int k = 0; k < 8; ++k) s = fmaf(x[k], gws[g * 8 + k], s);
                        float v = sigm(s);
                        if (c < 32) mixed[nb][row * MSTRIDE + c] = f2bf(v);
                        else        mtailb[nb][row * 2 + (c - 32)] = f2bf(v);
                    }
                }
            }
        }

        // ---- task phase: 8 tasks x 16 rows; every wave does all rows for its 64 cols ----
        for (int task = 0; task < 8; ++task) {
            // B-frag (verified): lane l, reg j -> B[k=(l>>4)*8+j][col=l&15], col=data-row
            short8 bfrag = *(const short8*)&mixed[cur][(task * 16 + li) * MSTRIDE + lg * 8];
            short8 b2f;
            {
                union { int i[4]; short8 s8; } ub;
                int mv = *(const int*)&mtailb[cur][(task * 16 + li) * 2];
                ub.i[0] = (lg == 0) ? mv : 0;          // {m32, m33}
                ub.i[1] = (lg == 0) ? 0x00003F80 : 0;  // {1.0bf16, 0}
                ub.i[2] = 0; ub.i[3] = 0;
                b2f = ub.s8;
            }
            float4_t z = {0.f, 0.f, 0.f, 0.f};
            float4_t c4[4];
            #pragma unroll
            for (int s = 0; s < 4; ++s)
                c4[s] = __builtin_amdgcn_mfma_f32_16x16x32_bf16(a2[s], b2f, z, 0, 0, 0);
            #pragma unroll
            for (int s = 0; s < 4; ++s)
                c4[s] = __builtin_amdgcn_mfma_f32_16x16x32_bf16(aW[s], bfrag, c4[s], 0, 0, 0);
            // D (verified): lane l holds D[c_local=lg*4+j][data_row=li]
            float p = 0.f;
            #pragma unroll
            for (int s = 0; s < 4; ++s)
                #pragma unroll
                for (int j = 0; j < 4; ++j)
                    p = fmaf(fmaxf(c4[s][j], 0.f), w2r[s][j], p);
            // sum over lg groups (cols) -> per-row partial for this wave's 64 cols
            p += __shfl_xor(p, 16, 64);
            p += __shfl_xor(p, 32, 64);
            if (lane < 16) partials[wave][task * 16 + lane] = p;
        }
        __syncthreads();  // partials ready AND next build complete

        if (tid < TILE) {
            float s = partials[0][tid] + partials[1][tid] + partials[2][tid] + partials[3][tid]
                    + partials[4][tid] + partials[5][tid] + partials[6][tid] + partials[7][tid];
            out[trow0 + tid] = sigm(s + b2v);
        }
        __syncthreads();  // partials consumed before next task phase overwrites
        cur ^= 1;
    }
}

extern "C" void kernel_launch(void* const* d_in, const int* in_sizes, int n_in,
                              void* d_out, int out_size, void* d_ws, size_t ws_size,
                              hipStream_t stream) {
    (void)in_sizes; (void)n_in; (void)out_size; (void)d_ws; (void)ws_size;
    const float* data = (const float*)d_in[0];
    const float* gW   = (const float*)d_in[1];
    const float* gb   = (const float*)d_in[2];
    const float* W1   = (const float*)d_in[3];
    const float* b1   = (const float*)d_in[4];
    const float* W2   = (const float*)d_in[5];
    const float* b2   = (const float*)d_in[6];
    float* out = (float*)d_out;
    fused_mfma_kernel<<<dim3(NBLK), dim3(NT), 0, stream>>>(data, gW, gb, W1, b1, W2, b2, out);
}

// Round 8
// 76.453 us; speedup vs baseline: 1.2584x; 1.0232x over previous
//
#include <hip/hip_runtime.h>
#include <hip/hip_bf16.h>

// Round 8: R4 skeleton (51.7us verified) with ONE change — the build phase is
// replaced by a row-per-wave coalesced scheme:
//   - lane l<42 loads float4 #l of the row's 168-float group region: the whole
//     region is ONE global_load_dwordx4 instruction per row per wave.
//   - gW lives in registers (lane l holds gW-float4 #l); pair-reduce via
//     shfl_xor(1); sigmoid on 21 even lanes; bf16 LDS write.
//   - lanes 43..55 load the 13 basic features (52B coalesced) and store bf16.
//   - 16 independent rows per wave, unroll 4 -> deep load pipeline (the R4-R7
//     binder was build-phase memory latency: L3-hot replays ran at cold speed).
// MFMA phase, W1f/wbt staging, overlap structure: verbatim R4 (verified varA).

#define B_ROWS 262144
#define DFEAT  181
#define BASICF 13
#define NG     21
#define MIXF   34
#define HID    512
#define NT     512
#define TILE   128
#define MSTRIDE 40                        // shorts per mixed row (80B)
#define ROWS_PER_BLOCK 512
#define NTILES (ROWS_PER_BLOCK / TILE)    // 4
#define NBLK   (B_ROWS / ROWS_PER_BLOCK)  // 512

typedef __attribute__((ext_vector_type(8))) short short8;
typedef __attribute__((ext_vector_type(4))) float float4_t;

__device__ __forceinline__ short f2bf(float f) {
    union { float f; unsigned u; } v; v.f = f;
    unsigned r = (v.u + 0x7FFFu + ((v.u >> 16) & 1u)) >> 16;  // RNE
    return (short)r;
}
__device__ __forceinline__ float sigm(float x) { return 1.0f / (1.0f + __expf(-x)); }

// 16B load at 4B alignment (group region starts at float index 13)
__device__ __forceinline__ float4_t load4u(const float* p) {
    float4_t v;
    __builtin_memcpy(&v, p, 16);
    return v;
}

// wave builds rows [wave*16, wave*16+16) of the 128-row tile at row0_global
__device__ __forceinline__ void build_rows(
    const float* __restrict__ data, int row0_global, int wave, int lane,
    float4_t gwv, float gbv, short* __restrict__ mixed, float* __restrict__ mtail)
{
    #pragma unroll 4
    for (int rr = 0; rr < 16; ++rr) {
        const int row = wave * 16 + rr;
        const float* dr = data + (size_t)(row0_global + row) * DFEAT;
        if (lane < 42) {
            float4_t x = load4u(dr + BASICF + lane * 4);
            float p = fmaf(x[0], gwv[0],
                      fmaf(x[1], gwv[1],
                      fmaf(x[2], gwv[2], x[3] * gwv[3])));
            p += __shfl_xor(p, 1, 64);      // pair (2g, 2g+1) -> full 8-wide dot
            if ((lane & 1) == 0) {
                int g = lane >> 1;           // 0..20
                float v = sigm(p + gbv);
                if (g < 19) mixed[row * MSTRIDE + BASICF + g] = f2bf(v);  // c=13..31
                else        mtail[row * 2 + (g - 19)] = v;                // c=32,33 f32
            }
        } else if (lane >= 43 && lane < 56) {
            int c = lane - 43;               // 0..12
            mixed[row * MSTRIDE + c] = f2bf(dr[c]);
        }
    }
}

__global__ __launch_bounds__(NT) void fused_mfma_kernel(
    const float* __restrict__ data, const float* __restrict__ gW,
    const float* __restrict__ gb, const float* __restrict__ W1,
    const float* __restrict__ b1, const float* __restrict__ W2,
    const float* __restrict__ b2, float* __restrict__ out)
{
    // LDS: 32768 + 8192 + 10240 + 1024 = 52224 B
    __shared__ __align__(16) short   W1f[32 * 64 * 8];    // B-frags k=0..31 (verified layout)
    __shared__ __align__(16) float4_t wbt[HID];           // {b1, W2, W1[32][c], W1[33][c]}
    __shared__ __align__(16) short   mixed[TILE * MSTRIDE];
    __shared__ __align__(8)  float   mtail[TILE * 2];     // {m32, m33} f32 per row

    const int tid = threadIdx.x;

    // ---- one-time staging (verbatim R4) ----
    for (int idx = tid; idx < 32 * HID; idx += NT) {
        int k = idx >> 9, c = idx & 511;
        int t = c >> 4, ci = c & 15;
        int l = ((k >> 3) << 4) + ci;
        int j = k & 7;
        W1f[(t * 64 + l) * 8 + j] = f2bf(W1[k * HID + c]);
    }
    {
        int c = tid;  // NT == HID
        wbt[c] = (float4_t){ b1[c], W2[c], W1[32 * HID + c], W1[33 * HID + c] };
    }

    const int wave = tid >> 6;
    const int lane = tid & 63;
    const int lg   = lane >> 4;   // 0..3
    const int li   = lane & 15;

    // gW/gb in registers: lane l holds gW-float4 #l (l<42) and gb[l>>1]
    float4_t gwv = {0.f, 0.f, 0.f, 0.f};
    float gbv = 0.f;
    if (lane < 42) {
        gwv = ((const float4_t*)gW)[lane];
        gbv = gb[lane >> 1];
    }
    const float b2v = b2[0];
    const int blk_row0 = blockIdx.x * ROWS_PER_BLOCK;
    __syncthreads();   // staging visible

    // ---- build tile 0 ----
    build_rows(data, blk_row0, wave, lane, gwv, gbv, mixed, mtail);
    __syncthreads();

    for (int tile = 0; tile < NTILES; ++tile) {
        const int trow0 = blk_row0 + tile * TILE;

        // secure A-frags (verified layout): lane l, reg j -> A[row=l&15][k=(l>>4)*8+j]
        short8 a0 = *(const short8*)&mixed[(wave * 16 + li) * MSTRIDE + lg * 8];
        float2 mt[4];
        #pragma unroll
        for (int j = 0; j < 4; ++j)
            mt[j] = *(const float2*)&mtail[(wave * 16 + lg * 4 + j) * 2];
        __syncthreads();  // all A-frags secured; mixed/mtail free for overwrite

        // build tile t+1 (overlaps MFMA below)
        if (tile + 1 < NTILES)
            build_rows(data, trow0 + TILE, wave, lane, gwv, gbv, mixed, mtail);

        // MFMA over 32 col-tiles (verified varA path + f32 rank-2 tail)
        float4_t acc = {0.f, 0.f, 0.f, 0.f};
        for (int t = 0; t < 32; ++t) {
            short8 bf = *(const short8*)&W1f[(t * 64 + lane) * 8];
            float4_t c4 = {0.f, 0.f, 0.f, 0.f};
            c4 = __builtin_amdgcn_mfma_f32_16x16x32_bf16(a0, bf, c4, 0, 0, 0);
            // C-frag (verified): lane l holds C[row=(l>>4)*4+j][col=t*16+(l&15)]
            int c = t * 16 + li;
            float4_t wv = wbt[c];  // {b1, W2, w32, w33}
            #pragma unroll
            for (int j = 0; j < 4; ++j) {
                float h = c4[j] + wv.x;
                h = fmaf(mt[j].x, wv.z, h);
                h = fmaf(mt[j].y, wv.w, h);
                h = fmaxf(h, 0.f);
                acc[j] = fmaf(h, wv.y, acc[j]);
            }
        }
        // reduce layer-2 partials across the 16 col-lanes (verified)
        #pragma unroll
        for (int m = 1; m < 16; m <<= 1) {
            #pragma unroll
            for (int j = 0; j < 4; ++j) acc[j] += __shfl_xor(acc[j], m, 64);
        }
        if (li == 0) {
            #pragma unroll
            for (int j = 0; j < 4; ++j)
                out[trow0 + wave * 16 + lg * 4 + j] = sigm(acc[j] + b2v);
        }
        __syncthreads();  // next iteration's A-frag reads need build complete
    }
}

extern "C" void kernel_launch(void* const* d_in, const int* in_sizes, int n_in,
                              void* d_out, int out_size, void* d_ws, size_t ws_size,
                              hipStream_t stream) {
    (void)in_sizes; (void)n_in; (void)out_size; (void)d_ws; (void)ws_size;
    const float* data = (const float*)d_in[0];
    const float* gW   = (const float*)d_in[1];
    const float* gb   = (const float*)d_in[2];
    const float* W1   = (const float*)d_in[3];
    const float* b1   = (const float*)d_in[4];
    const float* W2   = (const float*)d_in[5];
    const float* b2   = (const float*)d_in[6];
    float* out = (float*)d_out;
    fused_mfma_kernel<<<dim3(NBLK), dim3(NT), 0, stream>>>(data, gW, gb, W1, b1, W2, b2, out);
}

// Round 9
// 53.923 us; speedup vs baseline: 1.7842x; 1.4178x over previous
//
#include <hip/hip_runtime.h>
#include <hip/hip_bf16.h>

// Round 9: R8 code with ONE lever — occupancy 16 -> 32 waves/CU.
//   NT=1024 (16 waves/block), TILE=256, NTILES=2, grid 512 -> 2 blocks/CU,
//   32 waves/CU = 100% of wave slots (requires VGPR<=64; R8 compiled to 40).
//   LDS 63.5KB/block (2 blocks fit in 160KB).
// Build phase (wave-coalesced, verified in R8), MFMA phase, staging: verbatim R8.

#define B_ROWS 262144
#define DFEAT  181
#define BASICF 13
#define NG     21
#define MIXF   34
#define HID    512
#define NT     1024
#define TILE   256
#define MSTRIDE 40                        // shorts per mixed row (80B, 16B-aligned frags)
#define ROWS_PER_BLOCK 512
#define NTILES (ROWS_PER_BLOCK / TILE)    // 2
#define NBLK   (B_ROWS / ROWS_PER_BLOCK)  // 512

typedef __attribute__((ext_vector_type(8))) short short8;
typedef __attribute__((ext_vector_type(4))) float float4_t;

__device__ __forceinline__ short f2bf(float f) {
    union { float f; unsigned u; } v; v.f = f;
    unsigned r = (v.u + 0x7FFFu + ((v.u >> 16) & 1u)) >> 16;  // RNE
    return (short)r;
}
__device__ __forceinline__ float sigm(float x) { return 1.0f / (1.0f + __expf(-x)); }

// 16B load at 4B alignment (group region starts at float index 13)
__device__ __forceinline__ float4_t load4u(const float* p) {
    float4_t v;
    __builtin_memcpy(&v, p, 16);
    return v;
}

// wave builds rows [wave*16, wave*16+16) of the 256-row tile at row0_global
__device__ __forceinline__ void build_rows(
    const float* __restrict__ data, int row0_global, int wave, int lane,
    float4_t gwv, float gbv, short* __restrict__ mixed, float* __restrict__ mtail)
{
    #pragma unroll 4
    for (int rr = 0; rr < 16; ++rr) {
        const int row = wave * 16 + rr;
        const float* dr = data + (size_t)(row0_global + row) * DFEAT;
        if (lane < 42) {
            float4_t x = load4u(dr + BASICF + lane * 4);
            float p = fmaf(x[0], gwv[0],
                      fmaf(x[1], gwv[1],
                      fmaf(x[2], gwv[2], x[3] * gwv[3])));
            p += __shfl_xor(p, 1, 64);      // pair (2g, 2g+1) -> full 8-wide dot
            if ((lane & 1) == 0) {
                int g = lane >> 1;           // 0..20
                float v = sigm(p + gbv);
                if (g < 19) mixed[row * MSTRIDE + BASICF + g] = f2bf(v);  // c=13..31
                else        mtail[row * 2 + (g - 19)] = v;                // c=32,33 f32
            }
        } else if (lane >= 43 && lane < 56) {
            int c = lane - 43;               // 0..12
            mixed[row * MSTRIDE + c] = f2bf(dr[c]);
        }
    }
}

__global__ __launch_bounds__(NT) void fused_mfma_kernel(
    const float* __restrict__ data, const float* __restrict__ gW,
    const float* __restrict__ gb, const float* __restrict__ W1,
    const float* __restrict__ b1, const float* __restrict__ W2,
    const float* __restrict__ b2, float* __restrict__ out)
{
    // LDS: 32768 + 8192 + 20480 + 2048 = 63488 B -> 2 blocks/CU
    __shared__ __align__(16) short   W1f[32 * 64 * 8];    // B-frags k=0..31 (verified layout)
    __shared__ __align__(16) float4_t wbt[HID];           // {b1, W2, W1[32][c], W1[33][c]}
    __shared__ __align__(16) short   mixed[TILE * MSTRIDE];
    __shared__ __align__(8)  float   mtail[TILE * 2];     // {m32, m33} f32 per row

    const int tid = threadIdx.x;

    // ---- one-time staging (verbatim R4/R8) ----
    for (int idx = tid; idx < 32 * HID; idx += NT) {
        int k = idx >> 9, c = idx & 511;
        int t = c >> 4, ci = c & 15;
        int l = ((k >> 3) << 4) + ci;
        int j = k & 7;
        W1f[(t * 64 + l) * 8 + j] = f2bf(W1[k * HID + c]);
    }
    if (tid < HID) {
        int c = tid;
        wbt[c] = (float4_t){ b1[c], W2[c], W1[32 * HID + c], W1[33 * HID + c] };
    }

    const int wave = tid >> 6;
    const int lane = tid & 63;
    const int lg   = lane >> 4;   // 0..3
    const int li   = lane & 15;

    // gW/gb in registers: lane l holds gW-float4 #l (l<42) and gb[l>>1]
    float4_t gwv = {0.f, 0.f, 0.f, 0.f};
    float gbv = 0.f;
    if (lane < 42) {
        gwv = ((const float4_t*)gW)[lane];
        gbv = gb[lane >> 1];
    }
    const float b2v = b2[0];
    const int blk_row0 = blockIdx.x * ROWS_PER_BLOCK;
    __syncthreads();   // staging visible

    // ---- build tile 0 ----
    build_rows(data, blk_row0, wave, lane, gwv, gbv, mixed, mtail);
    __syncthreads();

    for (int tile = 0; tile < NTILES; ++tile) {
        const int trow0 = blk_row0 + tile * TILE;

        // secure A-frags (verified layout): lane l, reg j -> A[row=l&15][k=(l>>4)*8+j]
        short8 a0 = *(const short8*)&mixed[(wave * 16 + li) * MSTRIDE + lg * 8];
        float2 mt[4];
        #pragma unroll
        for (int j = 0; j < 4; ++j)
            mt[j] = *(const float2*)&mtail[(wave * 16 + lg * 4 + j) * 2];
        __syncthreads();  // all A-frags secured; mixed/mtail free for overwrite

        // build tile t+1 (overlaps MFMA below)
        if (tile + 1 < NTILES)
            build_rows(data, trow0 + TILE, wave, lane, gwv, gbv, mixed, mtail);

        // MFMA over 32 col-tiles (verified varA path + f32 rank-2 tail)
        float4_t acc = {0.f, 0.f, 0.f, 0.f};
        for (int t = 0; t < 32; ++t) {
            short8 bf = *(const short8*)&W1f[(t * 64 + lane) * 8];
            float4_t c4 = {0.f, 0.f, 0.f, 0.f};
            c4 = __builtin_amdgcn_mfma_f32_16x16x32_bf16(a0, bf, c4, 0, 0, 0);
            // C-frag (verified): lane l holds C[row=(l>>4)*4+j][col=t*16+(l&15)]
            int c = t * 16 + li;
            float4_t wv = wbt[c];  // {b1, W2, w32, w33}
            #pragma unroll
            for (int j = 0; j < 4; ++j) {
                float h = c4[j] + wv.x;
                h = fmaf(mt[j].x, wv.z, h);
                h = fmaf(mt[j].y, wv.w, h);
                h = fmaxf(h, 0.f);
                acc[j] = fmaf(h, wv.y, acc[j]);
            }
        }
        // reduce layer-2 partials across the 16 col-lanes (verified)
        #pragma unroll
        for (int m = 1; m < 16; m <<= 1) {
            #pragma unroll
            for (int j = 0; j < 4; ++j) acc[j] += __shfl_xor(acc[j], m, 64);
        }
        if (li == 0) {
            #pragma unroll
            for (int j = 0; j < 4; ++j)
                out[trow0 + wave * 16 + lg * 4 + j] = sigm(acc[j] + b2v);
        }
        __syncthreads();  // next iteration's A-frag reads need build complete
    }
}

extern "C" void kernel_launch(void* const* d_in, const int* in_sizes, int n_in,
                              void* d_out, int out_size, void* d_ws, size_t ws_size,
                              hipStream_t stream) {
    (void)in_sizes; (void)n_in; (void)out_size; (void)d_ws; (void)ws_size;
    const float* data = (const float*)d_in[0];
    const float* gW   = (const float*)d_in[1];
    const float* gb   = (const float*)d_in[2];
    const float* W1   = (const float*)d_in[3];
    const float* b1   = (const float*)d_in[4];
    const float* W2   = (const float*)d_in[5];
    const float* b2   = (const float*)d_in[6];
    float* out = (float*)d_out;
    fused_mfma_kernel<<<dim3(NBLK), dim3(NT), 0, stream>>>(data, gW, gb, W1, b1, W2, b2, out);
}